// Round 17
// baseline (196.001 us; speedup 1.0000x reference)
//
#include <hip/hip_runtime.h>

// FFLayer: out = relu( (x / (||x||_2 + 1e-4)) @ W^T + b )
// x: [131072,1024] f32, W: [256,1024] f32, b: [256] f32, out: [131072,256] f32
//
// Round 17: clean 512B-granularity probe. BM=64, 1024 thr, 16 waves (2Mx8N,
// 32x32 tiles). A-group = BK=128 (64 rows x 512B contiguous), 3 x 32KB,
// issued 2 groups ahead (insts at r=0,1 -> 4-8 steps landing slack).
// B = r8-verbatim 4 x 16KB, 3 ahead. Per-thread FIFO sim (no drains):
// prologue 4; steady r in {1,2} -> 4, r in {0,3} -> 3; tail 24-28 -> 2,
// 29 -> 1, >=30 -> 0. K-rotation by group (phg = blockIdx & 7).

#define IN_F   1024
#define OUT_F  256
#define BATCH  131072
#define BM     64
#define NKT    32      // BK=32 compute steps (8 groups of 4)
#define EPSV   1e-4f

typedef __attribute__((ext_vector_type(8))) __bf16 bf16x8;
typedef __attribute__((ext_vector_type(4))) __bf16 bf16x4;
typedef __attribute__((ext_vector_type(4))) float  f32x4;

__device__ __forceinline__ void gload_lds16(const void* g, void* lds) {
  __builtin_amdgcn_global_load_lds(
      (const __attribute__((address_space(1))) void*)g,
      (__attribute__((address_space(3))) void*)lds, 16, 0, 0);
}

#define VM_WAIT(N) do { asm volatile("s_waitcnt vmcnt(" #N ")" ::: "memory"); \
                        __builtin_amdgcn_sched_barrier(0); } while (0)

// W (f32 [256][1024]) -> bf16 [256][1024] in d_ws (512 KB)
__global__ void wconv_kernel(const float* __restrict__ W, __bf16* __restrict__ Wb) {
  const int t = blockIdx.x * blockDim.x + threadIdx.x;
  const float4 v = reinterpret_cast<const float4*>(W)[t];
  bf16x4 h;
  h[0] = (__bf16)v.x; h[1] = (__bf16)v.y; h[2] = (__bf16)v.z; h[3] = (__bf16)v.w;
  reinterpret_cast<bf16x4*>(Wb)[t] = h;
}

__global__ __launch_bounds__(1024, 4)
void ffl_kernel(const float* __restrict__ x, const __bf16* __restrict__ Wb,
                const float* __restrict__ bias, float* __restrict__ out) {
  // LDS (160KB exactly):
  //   A: 3 x 32KB at 0/32768/65536   f32 [64 rows][512B], granule^(row&7)
  //   B: 4 x 16KB at 98304..163840   bf16 [256 rows][64B], r8 layout
  //   norms: 256B at 163456 (tail of B[3], dead after the K-loop)
  //   epilogue stg [64][260] f32 = 66560B reuses A area
  __shared__ __align__(16) char smem[163840];
  char* const Ab[3] = {smem, smem + 32768, smem + 65536};
  char* const Bb[4] = {smem + 98304, smem + 114688, smem + 131072, smem + 147456};

  const int tid  = threadIdx.x;
  const int lane = tid & 63;
  const int wave = tid >> 6;     // 16 waves: 2(M) x 8(N), wave tile 32x32
  const int wr   = wave >> 3;    // 0..1, rows wr*32..+31
  const int wcn  = wave & 7;     // 0..7, cols wcn*32..+31
  const int rm   = lane & 15;
  const int q    = lane >> 4;
  const size_t block_row = (size_t)blockIdx.x * BM;
  const int phg = blockIdx.x & 7;             // K-rotation (8 A-groups)

  // ---- A staging: 2 insts/thread/group. Chunk c=2*wave+i (1KB = 2 rows x 512B).
  //      lane l -> row 2c+(l>>5), granule (l&31), src granule ^(row&7).
  const float* aSrc[2]; int aDst[2];
  #pragma unroll
  for (int i = 0; i < 2; ++i) {
    const int c   = 2 * wave + i;
    const int row = 2 * c + (lane >> 5);
    const int gs  = (lane & 31) ^ (row & 7);
    aSrc[i] = x + (block_row + row) * IN_F + gs * 4;
    aDst[i] = c * 1024;
  }
  // ---- B staging: 1 inst/thread/step. Chunk = wave (1KB = 16 rows x 64B).
  const int brow = 16 * wave + (lane >> 2);
  const int bs   = (lane & 3) ^ ((brow >> 1) & 3);
  const __bf16* bSrc = Wb + (size_t)brow * IN_F + bs * 8;
  const int bDst = wave * 1024;

  f32x4 acc[2][2];
  #pragma unroll
  for (int m = 0; m < 2; ++m)
    #pragma unroll
    for (int n = 0; n < 2; ++n)
      acc[m][n] = (f32x4){0.f, 0.f, 0.f, 0.f};

  float ssq0 = 0.f, ssq1 = 0.f;

  auto stageAinst = [&](int g, int i) {       // logical group -> phys (g+phg)&7
    const int pg = (g + phg) & 7;
    gload_lds16(aSrc[i] + pg * 128, Ab[g % 3] + aDst[i]);
  };
  auto stageB = [&](int kt) {                 // logical step -> phys (kt+4*phg)&31
    const int pk = (kt + 4 * phg) & 31;
    gload_lds16(bSrc + pk * 32, Bb[kt & 3] + bDst);
  };

  // -------- prologue: A0(2) B0 A1(2) B1 B2 = 7 insts --------
  stageAinst(0, 0); stageAinst(0, 1);
  stageB(0);
  stageAinst(1, 0); stageAinst(1, 1);
  stageB(1);
  stageB(2);
  VM_WAIT(4);                    // retire A0,B0; flight = [A1,A1,B1,B2]
  __builtin_amdgcn_s_barrier();

  // -------- main loop: 32 steps of BK=32 (8 groups of 4) --------
  #pragma unroll
  for (int kt = 0; kt < NKT; ++kt) {
    const int g = kt >> 2, r = kt & 3;

    if (kt + 3 < NKT) stageB(kt + 3);                  // 1 inst
    if (g + 2 <= 7) {                                  // A(g+2): r=0 -> #1, r=1 -> #2
      if (r == 0)      stageAinst(g + 2, 0);
      else if (r == 1) stageAinst(g + 2, 1);
    }

    const char* abuf = Ab[g % 3];
    const char* bbuf = Bb[kt & 3];
    const int   r8g  = r * 8;                 // granule window within 512B row

    // A fragments (f32 -> bf16) + exact sumsq: rows wr*32 + m*16 + rm
    bf16x8 aF[2];
    #pragma unroll
    for (int m = 0; m < 2; ++m) {
      const int ra = wr * 32 + m * 16 + rm;
      const char* ab = abuf + ra * 512;
      const int sw = ra & 7;
      const f32x4 lo = *reinterpret_cast<const f32x4*>(ab + ((r8g + 2 * q)     ^ sw) * 16);
      const f32x4 hi = *reinterpret_cast<const f32x4*>(ab + ((r8g + 2 * q + 1) ^ sw) * 16);
      float& ssq = m ? ssq1 : ssq0;
      ssq += lo[0]*lo[0] + lo[1]*lo[1] + lo[2]*lo[2] + lo[3]*lo[3]
           + hi[0]*hi[0] + hi[1]*hi[1] + hi[2]*hi[2] + hi[3]*hi[3];
      bf16x8 a;
      a[0]=(__bf16)lo[0]; a[1]=(__bf16)lo[1]; a[2]=(__bf16)lo[2]; a[3]=(__bf16)lo[3];
      a[4]=(__bf16)hi[0]; a[5]=(__bf16)hi[1]; a[6]=(__bf16)hi[2]; a[7]=(__bf16)hi[3];
      aF[m] = a;
    }

    #pragma unroll
    for (int n = 0; n < 2; ++n) {
      const int rb = wcn * 32 + n * 16 + rm;
      const bf16x8 bF = *reinterpret_cast<const bf16x8*>(
          bbuf + rb * 64 + (q ^ ((rb >> 1) & 3)) * 16);
      acc[0][n] = __builtin_amdgcn_mfma_f32_16x16x32_bf16(aF[0], bF, acc[0][n], 0, 0, 0);
      acc[1][n] = __builtin_amdgcn_mfma_f32_16x16x32_bf16(aF[1], bF, acc[1][n], 0, 0, 0);
    }

    // FIFO-simulated waits (min flight >= 2, no drains):
    if (kt >= 30)                            { VM_WAIT(0); }
    else if (kt == 29)                       { VM_WAIT(1); }
    else if (kt >= 24)                       { VM_WAIT(2); }
    else if ((kt & 3) == 1 || (kt & 3) == 2) { VM_WAIT(4); }
    else                                     { VM_WAIT(3); }
    __builtin_amdgcn_s_barrier();
  }

  // -------- row L2-norms: reduce over the 4 q-groups --------
  ssq0 += __shfl_xor(ssq0, 16); ssq0 += __shfl_xor(ssq0, 32);
  ssq1 += __shfl_xor(ssq1, 16); ssq1 += __shfl_xor(ssq1, 32);
  float* norms = reinterpret_cast<float*>(smem + 163456);  // B[3] tail, dead
  if (wcn == 0 && q == 0) {
    norms[wr * 32 + rm]      = 1.0f / (sqrtf(ssq0) + EPSV);
    norms[wr * 32 + 16 + rm] = 1.0f / (sqrtf(ssq1) + EPSV);
  }
  __syncthreads();

  // -------- scale + bias + relu -> LDS transpose (A area, dead) --------
  float* stg = reinterpret_cast<float*>(smem);   // [64][260] f32 = 66560B
  const int col0 = wcn * 32 + rm;
  #pragma unroll
  for (int n = 0; n < 2; ++n) {
    const float bn = bias[col0 + n * 16];
    #pragma unroll
    for (int m = 0; m < 2; ++m) {
      #pragma unroll
      for (int j = 0; j < 4; ++j) {
        const int lr = wr * 32 + m * 16 + q * 4 + j;
        stg[lr * 260 + col0 + n * 16] = fmaxf(acc[m][n][j] * norms[lr] + bn, 0.f);
      }
    }
  }
  __syncthreads();

  // -------- coalesced store: 64 rows x 256 cols, 16 thr/row --------
  const int rr = tid >> 4, p = tid & 15;
  const float* srow = stg + rr * 260;
  float* orow = out + (block_row + rr) * OUT_F;
  #pragma unroll
  for (int i = 0; i < 4; ++i) {
    const int f = i * 16 + p;                 // f32x4 index 0..63
    const f32x4 v = *reinterpret_cast<const f32x4*>(srow + f * 4);
    *reinterpret_cast<f32x4*>(orow + f * 4) = v;
  }
}

extern "C" void kernel_launch(void* const* d_in, const int* in_sizes, int n_in,
                              void* d_out, int out_size, void* d_ws, size_t ws_size,
                              hipStream_t stream) {
  const float* x = (const float*)d_in[0];
  const float* W = (const float*)d_in[1];
  const float* b = (const float*)d_in[2];
  float* out = (float*)d_out;
  __bf16* Wb = (__bf16*)d_ws;   // 512 KB scratch

  wconv_kernel<<<(OUT_F * IN_F / 4) / 256, 256, 0, stream>>>(W, Wb);
  ffl_kernel<<<BATCH / BM, 1024, 0, stream>>>(x, Wb, b, out);
}